// Round 17
// baseline (642.959 us; speedup 1.0000x reference)
//
#include <hip/hip_runtime.h>
#include <hip/hip_bf16.h>

typedef unsigned short u16;
typedef unsigned int u32;
typedef __attribute__((ext_vector_type(4))) float f32x4;
typedef __attribute__((ext_vector_type(8))) short short8;
typedef __attribute__((ext_vector_type(4))) unsigned short u16x4;
typedef __attribute__((ext_vector_type(2))) unsigned int u32x2;
typedef __attribute__((ext_vector_type(4))) unsigned int u32x4;

// B=32, T=64, I=H=512, V=32000, G=4H=2048, M=T*B=2048
#define LSTM_NBLK 16
#define LSTM_GRID 240   // 16 sync blocks + 224 Wout-conversion blocks

static __device__ __forceinline__ u16 f2bf(float f) {
  union { float f; unsigned u; } v; v.f = f;
  unsigned r = v.u + 0x7FFFu + ((v.u >> 16) & 1u);
  return (u16)(r >> 16);
}

static __device__ __forceinline__ void gload_lds16(const void* g, void* l) {
  __builtin_amdgcn_global_load_lds(
      (const __attribute__((address_space(1))) unsigned int*)g,
      (__attribute__((address_space(3))) unsigned int*)l, 16, 0, 0);
}

// --- L3-coherent (cross-XCD) access helpers: bypass L1/L2 ---
static __device__ __forceinline__ u32x4 ld_b128u_sc(const u32* p) {
  u32x4 r;
  asm volatile("global_load_dwordx4 %0, %1, off sc0 sc1"
               : "=v"(r) : "v"(p) : "memory");
  return r;
}
static __device__ __forceinline__ unsigned ld_u32_sc_wait(const u32* p) {
  unsigned r;
  asm volatile("global_load_dword %0, %1, off sc0 sc1\n\ts_waitcnt vmcnt(0)"
               : "=v"(r) : "v"(p) : "memory");
  return r;
}
static __device__ __forceinline__ void st_u32_sc(void* p, unsigned v) {
  asm volatile("global_store_dword %0, %1, off sc0 sc1"
               :: "v"(p), "v"(v) : "memory");
}
static __device__ __forceinline__ void st_u64_sc(void* p, u32 lo, u32 hi) {
  u32x2 v; v[0] = lo; v[1] = hi;
  asm volatile("global_store_dwordx2 %0, %1, off sc0 sc1"
               :: "v"(p), "v"(v) : "memory");
}
static __device__ __forceinline__ void waitcnt0() {
  asm volatile("s_waitcnt vmcnt(0)" ::: "memory");
  __builtin_amdgcn_sched_barrier(0);
}

// ---------------- prep: casts + transpose + tagged slot0 + clears ------------
__global__ void prep_kernel(const float* __restrict__ iseq, const float* __restrict__ h0,
                            const float* __restrict__ wih, const float* __restrict__ whh,
                            u16* __restrict__ wih_bf, u16* __restrict__ whh_bf,
                            u16* __restrict__ ax, u32* __restrict__ htag,
                            u32* __restrict__ h2u) {
  const int S0 = 262144;                  // Wih /4
  const int S1 = S0 + 262144;             // Whh /4
  const int S2 = S1 + 262144;             // ax /4
  const int S3 = S2 + 4096;               // htag slot 0 (16384 u32 /4)
  const int S4 = S3 + 258048;             // clear tags of slots 1..63
  const int S5 = S4 + 2048;               // h2 slot 0 (8192 u32 /4)
  int u = blockIdx.x * blockDim.x + threadIdx.x;
  int stride = gridDim.x * blockDim.x;
  for (; u < S5; u += stride) {
    if (u < S0) {
      int e = u * 4; f32x4 v = *(const f32x4*)(wih + e);
      u16x4 o; o[0]=f2bf(v[0]); o[1]=f2bf(v[1]); o[2]=f2bf(v[2]); o[3]=f2bf(v[3]);
      *(u16x4*)(wih_bf + e) = o;
    } else if (u < S1) {
      int e = (u - S0) * 4; f32x4 v = *(const f32x4*)(whh + e);
      u16x4 o; o[0]=f2bf(v[0]); o[1]=f2bf(v[1]); o[2]=f2bf(v[2]); o[3]=f2bf(v[3]);
      *(u16x4*)(whh_bf + e) = o;
    } else if (u < S2) {
      // A_x[m= t*32+b][k] = iseq[b][t][k]
      int e = (u - S1) * 4; int m = e >> 9; int k = e & 511;
      int b = m & 31; int t = m >> 5;
      f32x4 v = *(const f32x4*)(iseq + ((b * 64 + t) << 9) + k);
      u16x4 o; o[0]=f2bf(v[0]); o[1]=f2bf(v[1]); o[2]=f2bf(v[2]); o[3]=f2bf(v[3]);
      *(u16x4*)(ax + e) = o;
    } else if (u < S3) {
      // htag slot 0 = {tag=1, bf16(h0)}
      int e = (u - S2) * 4; f32x4 v = *(const f32x4*)(h0 + e);
      u32x4 o;
      o[0] = (1u << 16) | f2bf(v[0]); o[1] = (1u << 16) | f2bf(v[1]);
      o[2] = (1u << 16) | f2bf(v[2]); o[3] = (1u << 16) | f2bf(v[3]);
      *(u32x4*)(htag + e) = o;
    } else if (u < S4) {
      // clear tags of slots 1..63 (replay-safe: stale tags would alias)
      int e = (u - S3) * 4;
      u32x4 z = {0u, 0u, 0u, 0u};
      *(u32x4*)(htag + 16384 + e) = z;
    } else {
      // h2 slot 0 = bf16(h0) packed pairs
      int v = (u - S4) * 4;               // u32 index, 4 per iter
      int e = v * 2;                      // f32 element index
      f32x4 x0 = *(const f32x4*)(h0 + e);
      f32x4 x1 = *(const f32x4*)(h0 + e + 4);
      u32x4 o;
      o[0] = (((u32)f2bf(x0[1])) << 16) | (u32)f2bf(x0[0]);
      o[1] = (((u32)f2bf(x0[3])) << 16) | (u32)f2bf(x0[2]);
      o[2] = (((u32)f2bf(x1[1])) << 16) | (u32)f2bf(x1[0]);
      o[3] = (((u32)f2bf(x1[3])) << 16) | (u32)f2bf(x1[2]);
      *(u32x4*)(h2u + v) = o;
    }
  }
}

// ---------------- gemm1: C = A*Bw^T + bias1 + bias2 (m97-style 128x128) -----
__global__ __launch_bounds__(256, 2) void gemm_bt(
    const u16* __restrict__ A, const u16* __restrict__ Bw,
    float* __restrict__ C, const float* __restrict__ bias1,
    const float* __restrict__ bias2, int N) {
  __shared__ u16 As[2][8192];
  __shared__ u16 Bs[2][8192];
  const int tid = threadIdx.x;
  const int w = tid >> 6, l = tid & 63;
  const int wr = w >> 1, wc = w & 1;
  const int lid = blockIdx.x;
  const int cpx = gridDim.x >> 3;
  const int lid2 = (lid & 7) * cpx + (lid >> 3);
  const int tn = (lid2 >> 4) * 128;
  const int tm = (lid2 & 15) * 128;

  f32x4 acc[4][4];
#pragma unroll
  for (int i = 0; i < 4; ++i)
#pragma unroll
    for (int j = 0; j < 4; ++j) acc[i][j] = (f32x4){0.f, 0.f, 0.f, 0.f};

  auto stage = [&](int buf, int kt) {
#pragma unroll
    for (int i = 0; i < 4; ++i) {
      int r = (w * 4 + i) * 8 + (l >> 3);
      int c16 = (l & 7) ^ (r & 7);  // pre-swizzled source column
      const u16* srca = A + (tm + r) * 512 + kt * 64 + c16 * 8;
      gload_lds16(srca, &As[buf][(w * 4 + i) * 512]);
      const u16* srcb = Bw + (tn + r) * 512 + kt * 64 + c16 * 8;
      gload_lds16(srcb, &Bs[buf][(w * 4 + i) * 512]);
    }
  };

  stage(0, 0);
  int buf = 0;
  for (int kt = 0; kt < 8; ++kt) {
    __syncthreads();
    if (kt < 7) stage(buf ^ 1, kt + 1);
#pragma unroll
    for (int kk = 0; kk < 2; ++kk) {
      short8 af[4], bfr[4];
#pragma unroll
      for (int mi = 0; mi < 4; ++mi) {
        int row = wr * 64 + mi * 16 + (l & 15);
        int s = (kk * 4 + (l >> 4)) ^ (row & 7);
        af[mi] = *(const short8*)&As[buf][row * 64 + s * 8];
      }
#pragma unroll
      for (int ni = 0; ni < 4; ++ni) {
        int row = wc * 64 + ni * 16 + (l & 15);
        int s = (kk * 4 + (l >> 4)) ^ (row & 7);
        bfr[ni] = *(const short8*)&Bs[buf][row * 64 + s * 8];
      }
#pragma unroll
      for (int mi = 0; mi < 4; ++mi)
#pragma unroll
        for (int ni = 0; ni < 4; ++ni)
          acc[mi][ni] = __builtin_amdgcn_mfma_f32_16x16x32_bf16(
              af[mi], bfr[ni], acc[mi][ni], 0, 0, 0);
    }
    buf ^= 1;
  }

#pragma unroll
  for (int ni = 0; ni < 4; ++ni) {
    int gcol = tn + wc * 64 + ni * 16 + (l & 15);
    float bv = 0.f;
    if (bias1) bv += bias1[gcol];
    if (bias2) bv += bias2[gcol];
#pragma unroll
    for (int mi = 0; mi < 4; ++mi) {
      int grow0 = tm + wr * 64 + mi * 16 + ((l >> 4) << 2);
      f32x4 a = acc[mi][ni];
#pragma unroll
      for (int q = 0; q < 4; ++q) {
        C[(long long)(grow0 + q) * N + gcol] = a[q] + bv;
      }
    }
  }
}

// ---------------- gemm2: 256x128 tile, 3-slot rotating LDS, counted vmcnt ----
__global__ __launch_bounds__(512, 1) void gemm2_256(
    const u16* __restrict__ A, const u16* __restrict__ Bw,
    float* __restrict__ C, const float* __restrict__ bias, int N) {
  __shared__ u16 Asl[3][16384];   // 3 x 256x64 bf16 = 96 KB
  __shared__ u16 Bsl[3][8192];    // 3 x 128x64 bf16 = 48 KB
  const int tid = threadIdx.x;
  const int w = tid >> 6, l = tid & 63;
  const int wr = w >> 1, wc = w & 1;            // 4x2 wave grid
  const int lid = blockIdx.x;
  const int cpx = gridDim.x >> 3;               // 2000/8 = 250
  const int lid2 = (lid & 7) * cpx + (lid >> 3);
  const int tm = (lid2 & 7) * 256;              // tm fastest within XCD chunk
  const int tn = (lid2 >> 3) * 128;

  f32x4 acc[4][4];
#pragma unroll
  for (int i = 0; i < 4; ++i)
#pragma unroll
    for (int j = 0; j < 4; ++j) acc[i][j] = (f32x4){0.f, 0.f, 0.f, 0.f};

  auto stage = [&](int slot, int kt) {
#pragma unroll
    for (int j = 0; j < 4; ++j) {
      int chunk = w * 4 + j;
      int r = chunk * 8 + (l >> 3);
      int c16 = (l & 7) ^ (r & 7);            // pre-swizzled source column
      int rowm = tm + r;
      const u16* srca = A + ((rowm & 63) + 1) * 16384 + (rowm >> 6) * 512
                          + kt * 64 + c16 * 8;
      gload_lds16(srca, &Asl[slot][chunk * 512]);
    }
#pragma unroll
    for (int j = 0; j < 2; ++j) {
      int chunk = w * 2 + j;
      int r = chunk * 8 + (l >> 3);
      int c16 = (l & 7) ^ (r & 7);
      const u16* srcb = Bw + (tn + r) * 512 + kt * 64 + c16 * 8;
      gload_lds16(srcb, &Bsl[slot][chunk * 512]);
    }
  };

  stage(0, 0);
  stage(1, 1);
  for (int kt = 0; kt < 8; ++kt) {
    const int slot = kt % 3;
    if (kt < 7) {
      asm volatile("s_waitcnt vmcnt(6)" ::: "memory");
    } else {
      asm volatile("s_waitcnt vmcnt(0)" ::: "memory");
    }
    __builtin_amdgcn_sched_barrier(0);
    __builtin_amdgcn_s_barrier();
    __builtin_amdgcn_sched_barrier(0);
    if (kt < 6) stage((kt + 2) % 3, kt + 2);
#pragma unroll
    for (int kk = 0; kk < 2; ++kk) {
      short8 bfr[4];
#pragma unroll
      for (int ni = 0; ni < 4; ++ni) {
        int row = wc * 64 + ni * 16 + (l & 15);
        int s = (kk * 4 + (l >> 4)) ^ (row & 7);
        bfr[ni] = *(const short8*)&Bsl[slot][row * 64 + s * 8];
      }
#pragma unroll
      for (int mi = 0; mi < 4; ++mi) {
        int row = wr * 64 + mi * 16 + (l & 15);
        int s = (kk * 4 + (l >> 4)) ^ (row & 7);
        short8 af = *(const short8*)&Asl[slot][row * 64 + s * 8];
#pragma unroll
        for (int ni = 0; ni < 4; ++ni)
          acc[mi][ni] = __builtin_amdgcn_mfma_f32_16x16x32_bf16(
              af, bfr[ni], acc[mi][ni], 0, 0, 0);
      }
    }
  }

#pragma unroll
  for (int ni = 0; ni < 4; ++ni) {
    int gcol = tn + wc * 64 + ni * 16 + (l & 15);
    float bv = bias[gcol];
#pragma unroll
    for (int mi = 0; mi < 4; ++mi) {
      int grow0 = tm + wr * 64 + mi * 16 + ((l >> 4) << 2);
      f32x4 a = acc[mi][ni];
#pragma unroll
      for (int q = 0; q < 4; ++q) {
        C[(long long)(grow0 + q) * N + gcol] = a[q] + bv;
      }
    }
  }
}

// ---------------- persistent LSTM recurrence: tagged data + sentinel poll ----
// Blocks 0..15: per step, producers publish tagged u32 {tag=it+2, bf16}
// fire-and-forget (NO drain, NO flag). Each half-wave polls ONE sentinel word
// of its producer's slice (same poll traffic as the flag scheme: 16 lines/
// block/round); after it hits, threads bulk-fetch their 128B tagged chunk and
// validate every tag (retry on stragglers — rare, stores land together).
// Own-block slice short-circuits via hloc. Chain: store flight -> sentinel RT
// -> fetch RT = ~2 coherent hops vs 4. Blocks 16..239: Wout f32->bf16 cast.
__global__ __launch_bounds__(512, 1) void lstm_persist(
    const u16* __restrict__ whh, const float* __restrict__ xg,
    u32* __restrict__ htag, u32* __restrict__ h2u,
    const float* __restrict__ wout, u16* __restrict__ wout_bf) {
  __shared__ u16 hbuf[32 * 512];
  __shared__ u16 hloc[1024];
  const int tid = threadIdx.x;

  if (blockIdx.x >= LSTM_NBLK) {
    int idx = (blockIdx.x - LSTM_NBLK) * 512 + tid;
    int stride = (LSTM_GRID - LSTM_NBLK) * 512;
    for (int u2 = idx; u2 < 4096000; u2 += stride) {
      int e = u2 * 4; f32x4 v = *(const f32x4*)(wout + e);
      u16x4 o; o[0]=f2bf(v[0]); o[1]=f2bf(v[1]); o[2]=f2bf(v[2]); o[3]=f2bf(v[3]);
      *(u16x4*)(wout_bf + e) = o;
    }
    return;
  }

  const int w = tid >> 6, l = tid & 63;
  const int blk = blockIdx.x;
  const int j0 = (blk * 8 + w) * 4;                // wave's 4 h-columns
  const int c = l & 15;
  const int wrow = (c >> 2) * 512 + j0 + (c & 3);  // W_hh row == gate column
  const int ko = (l >> 4) * 8;

  short8 bfr[16];
  const u16* wp = whh + wrow * 512 + ko;
#pragma unroll
  for (int kt = 0; kt < 16; ++kt) bfr[kt] = *(const short8*)(wp + kt * 32);

  const int rq = (l >> 4) * 4;
  const int jj = l & 3;
  const int b0 = l & 15, b1 = 16 + (l & 15);
  const int s0 = b0 & 7;

  // consumer mapping: thread covers (row cb, 32 u32 at ckg*32); ckg = producer
  const int cb = tid & 31;
  const int ckg = tid >> 5;        // 0..15
  const int csw = cb & 7;

  // publish mapping: thread stores cols pj*2, pj*2+1 of row pb
  const int pb = tid >> 4;         // 0..31
  const int pj = tid & 15;         // 0..15

  float creg[2][4];
#pragma unroll
  for (int mt = 0; mt < 2; ++mt)
#pragma unroll
    for (int q = 0; q < 4; ++q) creg[mt][q] = 0.f;

  float xcur[2][4], xnext[2][4];
#pragma unroll
  for (int mt = 0; mt < 2; ++mt)
#pragma unroll
    for (int q = 0; q < 4; ++q)
      xcur[mt][q] = xg[(mt * 16 + rq + q) * 2048 + wrow];

  for (int it = 0; it < 64; ++it) {
    const unsigned want = (unsigned)(it + 1);
    const bool ownp = (ckg == blk);
    // ---- (A) sentinel: half-wave polls 1 word of its producer's slice ----
    if (it > 0) {
      const u32* sen = htag + it * 16384 + ckg * 32;  // row 0, producer ckg
      for (;;) {
        unsigned f = ownp ? (want << 16) : ld_u32_sc_wait(sen);
        if (__all((int)((f >> 16) == want))) break;
      }
    }
    // ---- (B) fetch own 128B tagged chunk, validate, stage -> swizzled LDS ----
    short8 d0, d1, d2, d3;
    if (ownp && it > 0) {
      d0 = *(const short8*)&hloc[cb * 32 + 0];
      d1 = *(const short8*)&hloc[cb * 32 + 8];
      d2 = *(const short8*)&hloc[cb * 32 + 16];
      d3 = *(const short8*)&hloc[cb * 32 + 24];
    } else {
      const u32* src = htag + it * 16384 + cb * 512 + ckg * 32;
      u32x4 a0, a1, a2, a3, a4, a5, a6, a7;
      for (;;) {
        a0 = ld_b128u_sc(src +  0); a1 = ld_b128u_sc(src +  4);
        a2 = ld_b128u_sc(src +  8); a3 = ld_b128u_sc(src + 12);
        a4 = ld_b128u_sc(src + 16); a5 = ld_b128u_sc(src + 20);
        a6 = ld_b128u_sc(src + 24); a7 = ld_b128u_sc(src + 28);
        waitcnt0();
        unsigned d = 0;
#pragma unroll
        for (int q2 = 0; q2 < 4; ++q2) {
          d |= (a0[q2] >> 16) ^ want; d |= (a1[q2] >> 16) ^ want;
          d |= (a2[q2] >> 16) ^ want; d |= (a3[q2] >> 16) ^ want;
          d |= (a4[q2] >> 16) ^ want; d |= (a5[q2] >> 16) ^ want;
          d |= (a6[q2] >> 16) ^ want; d |= (a7[q2] >> 16) ^ want;
        }
        if (d == 0) break;  // per-lane retry for straggler stores (rare)
      }
      d0[0]=(short)a0[0]; d0[1]=(short)a0[1]; d0[2]=(short)a0[2]; d0[3]=(short)a0[3];
      d0[4]=(short)a1[0]; d0[5]=(short)a1[1]; d0[6]=(short)a1[2]; d0[7]=(short)a1[3];
      d1[0]=(short)a2[0]; d1[1]=(short)a2[1]; d1[2]=(short)a2[2]; d1[3]=(short)a2[3];
      d1[4]=(short)a3[0]; d1[5]=(short)a3[1]; d1[6]=(short)a3[2]; d1[7]=(short)a3[3];
      d2[0]=(short)a4[0]; d2[1]=(short)a4[1]; d2[2]=(short)a4[2]; d2[3]=(short)a4[3];
      d2[4]=(short)a5[0]; d2[5]=(short)a5[1]; d2[6]=(short)a5[2]; d2[7]=(short)a5[3];
      d3[0]=(short)a6[0]; d3[1]=(short)a6[1]; d3[2]=(short)a6[2]; d3[3]=(short)a6[3];
      d3[4]=(short)a7[0]; d3[5]=(short)a7[1]; d3[6]=(short)a7[2]; d3[7]=(short)a7[3];
    }
    *(short8*)&hbuf[cb * 512 + (((ckg * 4 + 0) ^ csw) * 8)] = d0;
    *(short8*)&hbuf[cb * 512 + (((ckg * 4 + 1) ^ csw) * 8)] = d1;
    *(short8*)&hbuf[cb * 512 + (((ckg * 4 + 2) ^ csw) * 8)] = d2;
    *(short8*)&hbuf[cb * 512 + (((ckg * 4 + 3) ^ csw) * 8)] = d3;
    __syncthreads();   // S1: hbuf ready (also orders hloc reads before D)

    // ---- (C) MFMA: gates = h_{prev} @ W_hh^T ----
    f32x4 acc0 = (f32x4){0.f, 0.f, 0.f, 0.f};
    f32x4 acc1 = (f32x4){0.f, 0.f, 0.f, 0.f};
#pragma unroll
    for (int kt = 0; kt < 16; ++kt) {
      int x = ((kt * 4 + (l >> 4)) ^ s0) * 8;
      short8 a0 = *(const short8*)&hbuf[b0 * 512 + x];
      short8 a1 = *(const short8*)&hbuf[b1 * 512 + x];
      acc0 = __builtin_amdgcn_mfma_f32_16x16x32_bf16(a0, bfr[kt], acc0, 0, 0, 0);
      acc1 = __builtin_amdgcn_mfma_f32_16x16x32_bf16(a1, bfr[kt], acc1, 0, 0, 0);
    }
    if (it < 63) {
#pragma unroll
      for (int mt = 0; mt < 2; ++mt)
#pragma unroll
        for (int q = 0; q < 4; ++q)
          xnext[mt][q] = xg[((it + 1) * 32 + mt * 16 + rq + q) * 2048 + wrow];
    }

    // ---- (D) pointwise LSTM cell -> hloc ----
#pragma unroll
    for (int mt = 0; mt < 2; ++mt) {
#pragma unroll
      for (int q = 0; q < 4; ++q) {
        float av = (mt == 0) ? acc0[q] : acc1[q];
        float gp = av + xcur[mt][q];
        int bl = (l & 48) | jj;
        float xi = __shfl(gp, bl);
        float xf = __shfl(gp, bl | 4);
        float xgg = __shfl(gp, bl | 8);
        float xo = __shfl(gp, bl | 12);
        float is = 1.f / (1.f + __expf(-xi));
        float fs = 1.f / (1.f + __expf(-xf));
        float e2 = __expf(2.f * xgg);
        float gt = 1.f - 2.f / (e2 + 1.f);       // tanh, inf-safe
        float os = 1.f / (1.f + __expf(-xo));
        float cn = fs * creg[mt][q] + is * gt;
        creg[mt][q] = cn;
        float e2c = __expf(2.f * cn);
        float hn = os * (1.f - 2.f / (e2c + 1.f));
        if ((l & 12) == 0) {
          int b = mt * 16 + rq + q;
          hloc[b * 32 + w * 4 + jj] = f2bf(hn);
        }
      }
    }
    __syncthreads();   // S2: hloc complete; hbuf C-reads complete

    // ---- (E) publish: tagged (fire-and-forget) + plain h2 for gemm2 ----
    {
      u32 lo = (u32)hloc[pb * 32 + pj * 2];
      u32 hi = (u32)hloc[pb * 32 + pj * 2 + 1];
      if (it < 63) {
        u32 tag = ((u32)(it + 2)) << 16;
        st_u64_sc(htag + (it + 1) * 16384 + pb * 512 + blk * 32 + pj * 2,
                  tag | lo, tag | hi);
      }
      st_u32_sc(h2u + (it + 1) * 8192 + pb * 256 + blk * 16 + pj,
                (hi << 16) | lo);
    }
    if (it < 63) {
#pragma unroll
      for (int mt = 0; mt < 2; ++mt)
#pragma unroll
        for (int q = 0; q < 4; ++q)
          xcur[mt][q] = xnext[mt][q];
    }
    // no drain, no flag, no trailing barrier: next step's S1 orders reuse
  }
}

extern "C" void kernel_launch(void* const* d_in, const int* in_sizes, int n_in,
                              void* d_out, int out_size, void* d_ws, size_t ws_size,
                              hipStream_t stream) {
  (void)in_sizes; (void)n_in; (void)out_size; (void)ws_size;
  const float* iseq = (const float*)d_in[0];
  const float* h0   = (const float*)d_in[1];
  const float* wih  = (const float*)d_in[2];
  const float* whh  = (const float*)d_in[3];
  const float* bih  = (const float*)d_in[4];
  const float* bhh  = (const float*)d_in[5];
  const float* wout = (const float*)d_in[6];
  const float* bout = (const float*)d_in[7];

  char* ws = (char*)d_ws;
  u16* wout_bf = (u16*)(ws + 0);             // 32,768,000
  u16* wih_bf  = (u16*)(ws + 32768000);      // 2,097,152
  u16* whh_bf  = (u16*)(ws + 34865152);      // 2,097,152
  u16* ax      = (u16*)(ws + 36962304);      // 2,097,152
  u16* h2      = (u16*)(ws + 39059456);      // 65 slots x 32,768 = 2,129,920
  u32* htag    = (u32*)(ws + 41189376);      // 64 slots x 65,536 = 4,194,304
  float* xg    = (float*)(ws + 45383680);    // 16,777,216  (end 62,160,896)
  float* out   = (float*)d_out;

  prep_kernel<<<2048, 256, 0, stream>>>(iseq, h0, wih, whh,
                                        wih_bf, whh_bf, ax, htag, (u32*)h2);
  // x_gates = A_x @ W_ih^T + b_ih + b_hh   -> xg [2048][2048] f32
  gemm_bt<<<256, 256, 0, stream>>>(ax, wih_bf, xg, bih, bhh, 2048);
  // persistent recurrence (16 sync blocks, tagged sentinel) + Wout cast
  lstm_persist<<<LSTM_GRID, 512, 0, stream>>>(whh_bf, xg, htag, (u32*)h2,
                                              wout, wout_bf);
  // logits = h @ W_out^T + b_out -> d_out [2048][32000] f32
  gemm2_256<<<2000, 512, 0, stream>>>(h2, wout_bf, out, bout, 32000);
}

// Round 18
// 522.352 us; speedup vs baseline: 1.2309x; 1.2309x over previous
//
#include <hip/hip_runtime.h>
#include <hip/hip_bf16.h>

typedef unsigned short u16;
typedef unsigned int u32;
typedef __attribute__((ext_vector_type(4))) float f32x4;
typedef __attribute__((ext_vector_type(8))) short short8;
typedef __attribute__((ext_vector_type(4))) unsigned short u16x4;
typedef __attribute__((ext_vector_type(4))) unsigned int u32x4;

// B=32, T=64, I=H=512, V=32000, G=4H=2048, M=T*B=2048
#define LSTM_NBLK 16
#define LSTM_GRID 240   // 16 sync blocks + 224 Wout-conversion blocks

static __device__ __forceinline__ u16 f2bf(float f) {
  union { float f; unsigned u; } v; v.f = f;
  unsigned r = v.u + 0x7FFFu + ((v.u >> 16) & 1u);
  return (u16)(r >> 16);
}

static __device__ __forceinline__ void gload_lds16(const void* g, void* l) {
  __builtin_amdgcn_global_load_lds(
      (const __attribute__((address_space(1))) unsigned int*)g,
      (__attribute__((address_space(3))) unsigned int*)l, 16, 0, 0);
}

// --- L3-coherent (cross-XCD) access helpers: bypass L1/L2 ---
static __device__ __forceinline__ short8 ld_b128_sc(const void* p) {
  short8 r;
  asm volatile("global_load_dwordx4 %0, %1, off sc0 sc1"
               : "=v"(r) : "v"(p) : "memory");
  return r;
}
static __device__ __forceinline__ unsigned ld_u32_sc_wait(const unsigned* p) {
  unsigned r;
  asm volatile("global_load_dword %0, %1, off sc0 sc1\n\ts_waitcnt vmcnt(0)"
               : "=v"(r) : "v"(p) : "memory");
  return r;
}
static __device__ __forceinline__ void st_u32_sc(void* p, unsigned v) {
  asm volatile("global_store_dword %0, %1, off sc0 sc1"
               :: "v"(p), "v"(v) : "memory");
}
static __device__ __forceinline__ void waitcnt0() {
  asm volatile("s_waitcnt vmcnt(0)" ::: "memory");
  __builtin_amdgcn_sched_barrier(0);
}

// ---------------- prep: small casts + transpose + h2 slot0 + flag init -------
__global__ void prep_kernel(const float* __restrict__ iseq, const float* __restrict__ h0,
                            const float* __restrict__ wih, const float* __restrict__ whh,
                            u16* __restrict__ wih_bf, u16* __restrict__ whh_bf,
                            u16* __restrict__ ax, u32* __restrict__ h2u,
                            unsigned* __restrict__ flags) {
  const int S0 = 262144;                  // Wih /4
  const int S1 = S0 + 262144;             // Whh /4
  const int S2 = S1 + 262144;             // ax /4
  const int S3 = S2 + 8192;               // h2 slot 0 (8192 u32)
  const int S4 = S3 + 4096;               // flags 16 rows x 256 u32
  int u = blockIdx.x * blockDim.x + threadIdx.x;
  int stride = gridDim.x * blockDim.x;
  for (; u < S4; u += stride) {
    if (u < S0) {
      int e = u * 4; f32x4 v = *(const f32x4*)(wih + e);
      u16x4 o; o[0]=f2bf(v[0]); o[1]=f2bf(v[1]); o[2]=f2bf(v[2]); o[3]=f2bf(v[3]);
      *(u16x4*)(wih_bf + e) = o;
    } else if (u < S1) {
      int e = (u - S0) * 4; f32x4 v = *(const f32x4*)(whh + e);
      u16x4 o; o[0]=f2bf(v[0]); o[1]=f2bf(v[1]); o[2]=f2bf(v[2]); o[3]=f2bf(v[3]);
      *(u16x4*)(whh_bf + e) = o;
    } else if (u < S2) {
      // A_x[m= t*32+b][k] = iseq[b][t][k]
      int e = (u - S1) * 4; int m = e >> 9; int k = e & 511;
      int b = m & 31; int t = m >> 5;
      f32x4 v = *(const f32x4*)(iseq + ((b * 64 + t) << 9) + k);
      u16x4 o; o[0]=f2bf(v[0]); o[1]=f2bf(v[1]); o[2]=f2bf(v[2]); o[3]=f2bf(v[3]);
      *(u16x4*)(ax + e) = o;
    } else if (u < S3) {
      // h2 slot 0 = bf16(h0), [32][512] u16 packed as u32 pairs
      int v = u - S2;                    // 0..8191
      int e = v * 2;                     // f32 element index into h0
      float lo = h0[e], hi = h0[e + 1];
      h2u[v] = (((u32)f2bf(hi)) << 16) | (u32)f2bf(lo);
    } else {
      flags[u - S3] = 0u;
    }
  }
}

// ---------------- gemm1: C = A*Bw^T + bias1 + bias2 (m97-style 128x128) -----
__global__ __launch_bounds__(256, 2) void gemm_bt(
    const u16* __restrict__ A, const u16* __restrict__ Bw,
    float* __restrict__ C, const float* __restrict__ bias1,
    const float* __restrict__ bias2, int N) {
  __shared__ u16 As[2][8192];
  __shared__ u16 Bs[2][8192];
  const int tid = threadIdx.x;
  const int w = tid >> 6, l = tid & 63;
  const int wr = w >> 1, wc = w & 1;
  const int lid = blockIdx.x;
  const int cpx = gridDim.x >> 3;
  const int lid2 = (lid & 7) * cpx + (lid >> 3);
  const int tn = (lid2 >> 4) * 128;
  const int tm = (lid2 & 15) * 128;

  f32x4 acc[4][4];
#pragma unroll
  for (int i = 0; i < 4; ++i)
#pragma unroll
    for (int j = 0; j < 4; ++j) acc[i][j] = (f32x4){0.f, 0.f, 0.f, 0.f};

  auto stage = [&](int buf, int kt) {
#pragma unroll
    for (int i = 0; i < 4; ++i) {
      int r = (w * 4 + i) * 8 + (l >> 3);
      int c16 = (l & 7) ^ (r & 7);  // pre-swizzled source column
      const u16* srca = A + (tm + r) * 512 + kt * 64 + c16 * 8;
      gload_lds16(srca, &As[buf][(w * 4 + i) * 512]);
      const u16* srcb = Bw + (tn + r) * 512 + kt * 64 + c16 * 8;
      gload_lds16(srcb, &Bs[buf][(w * 4 + i) * 512]);
    }
  };

  stage(0, 0);
  int buf = 0;
  for (int kt = 0; kt < 8; ++kt) {
    __syncthreads();
    if (kt < 7) stage(buf ^ 1, kt + 1);
#pragma unroll
    for (int kk = 0; kk < 2; ++kk) {
      short8 af[4], bfr[4];
#pragma unroll
      for (int mi = 0; mi < 4; ++mi) {
        int row = wr * 64 + mi * 16 + (l & 15);
        int s = (kk * 4 + (l >> 4)) ^ (row & 7);
        af[mi] = *(const short8*)&As[buf][row * 64 + s * 8];
      }
#pragma unroll
      for (int ni = 0; ni < 4; ++ni) {
        int row = wc * 64 + ni * 16 + (l & 15);
        int s = (kk * 4 + (l >> 4)) ^ (row & 7);
        bfr[ni] = *(const short8*)&Bs[buf][row * 64 + s * 8];
      }
#pragma unroll
      for (int mi = 0; mi < 4; ++mi)
#pragma unroll
        for (int ni = 0; ni < 4; ++ni)
          acc[mi][ni] = __builtin_amdgcn_mfma_f32_16x16x32_bf16(
              af[mi], bfr[ni], acc[mi][ni], 0, 0, 0);
    }
    buf ^= 1;
  }

#pragma unroll
  for (int ni = 0; ni < 4; ++ni) {
    int gcol = tn + wc * 64 + ni * 16 + (l & 15);
    float bv = 0.f;
    if (bias1) bv += bias1[gcol];
    if (bias2) bv += bias2[gcol];
#pragma unroll
    for (int mi = 0; mi < 4; ++mi) {
      int grow0 = tm + wr * 64 + mi * 16 + ((l >> 4) << 2);
      f32x4 a = acc[mi][ni];
#pragma unroll
      for (int q = 0; q < 4; ++q) {
        C[(long long)(grow0 + q) * N + gcol] = a[q] + bv;
      }
    }
  }
}

// ---------------- gemm2: 256x128 tile, 3-slot rotating LDS, counted vmcnt ----
__global__ __launch_bounds__(512, 1) void gemm2_256(
    const u16* __restrict__ A, const u16* __restrict__ Bw,
    float* __restrict__ C, const float* __restrict__ bias, int N) {
  __shared__ u16 Asl[3][16384];   // 3 x 256x64 bf16 = 96 KB
  __shared__ u16 Bsl[3][8192];    // 3 x 128x64 bf16 = 48 KB
  const int tid = threadIdx.x;
  const int w = tid >> 6, l = tid & 63;
  const int wr = w >> 1, wc = w & 1;            // 4x2 wave grid
  const int lid = blockIdx.x;
  const int cpx = gridDim.x >> 3;               // 2000/8 = 250
  const int lid2 = (lid & 7) * cpx + (lid >> 3);
  const int tm = (lid2 & 7) * 256;              // tm fastest within XCD chunk
  const int tn = (lid2 >> 3) * 128;

  f32x4 acc[4][4];
#pragma unroll
  for (int i = 0; i < 4; ++i)
#pragma unroll
    for (int j = 0; j < 4; ++j) acc[i][j] = (f32x4){0.f, 0.f, 0.f, 0.f};

  auto stage = [&](int slot, int kt) {
#pragma unroll
    for (int j = 0; j < 4; ++j) {
      int chunk = w * 4 + j;
      int r = chunk * 8 + (l >> 3);
      int c16 = (l & 7) ^ (r & 7);            // pre-swizzled source column
      int rowm = tm + r;
      const u16* srca = A + ((rowm & 63) + 1) * 16384 + (rowm >> 6) * 512
                          + kt * 64 + c16 * 8;
      gload_lds16(srca, &Asl[slot][chunk * 512]);
    }
#pragma unroll
    for (int j = 0; j < 2; ++j) {
      int chunk = w * 2 + j;
      int r = chunk * 8 + (l >> 3);
      int c16 = (l & 7) ^ (r & 7);
      const u16* srcb = Bw + (tn + r) * 512 + kt * 64 + c16 * 8;
      gload_lds16(srcb, &Bsl[slot][chunk * 512]);
    }
  };

  stage(0, 0);
  stage(1, 1);
  for (int kt = 0; kt < 8; ++kt) {
    const int slot = kt % 3;
    if (kt < 7) {
      asm volatile("s_waitcnt vmcnt(6)" ::: "memory");
    } else {
      asm volatile("s_waitcnt vmcnt(0)" ::: "memory");
    }
    __builtin_amdgcn_sched_barrier(0);
    __builtin_amdgcn_s_barrier();
    __builtin_amdgcn_sched_barrier(0);
    if (kt < 6) stage((kt + 2) % 3, kt + 2);
#pragma unroll
    for (int kk = 0; kk < 2; ++kk) {
      short8 bfr[4];
#pragma unroll
      for (int ni = 0; ni < 4; ++ni) {
        int row = wc * 64 + ni * 16 + (l & 15);
        int s = (kk * 4 + (l >> 4)) ^ (row & 7);
        bfr[ni] = *(const short8*)&Bsl[slot][row * 64 + s * 8];
      }
#pragma unroll
      for (int mi = 0; mi < 4; ++mi) {
        int row = wr * 64 + mi * 16 + (l & 15);
        int s = (kk * 4 + (l >> 4)) ^ (row & 7);
        short8 af = *(const short8*)&Asl[slot][row * 64 + s * 8];
#pragma unroll
        for (int ni = 0; ni < 4; ++ni)
          acc[mi][ni] = __builtin_amdgcn_mfma_f32_16x16x32_bf16(
              af, bfr[ni], acc[mi][ni], 0, 0, 0);
      }
    }
  }

#pragma unroll
  for (int ni = 0; ni < 4; ++ni) {
    int gcol = tn + wc * 64 + ni * 16 + (l & 15);
    float bv = bias[gcol];
#pragma unroll
    for (int mi = 0; mi < 4; ++mi) {
      int grow0 = tm + wr * 64 + mi * 16 + ((l >> 4) << 2);
      f32x4 a = acc[mi][ni];
#pragma unroll
      for (int q = 0; q < 4; ++q) {
        C[(long long)(grow0 + q) * N + gcol] = a[q] + bv;
      }
    }
  }
}

// ---------------- persistent LSTM recurrence + Wout conversion on idle CUs ---
// Blocks 0..15: measured-best protocol with per-wave poll-and-fetch: wave w
// owns producers 2w,2w+1 (== its staging ckg range); it polls only those 2
// flag lines and stages their slices as soon as THEY are ready. Blocks
// 16..239: Wout f32->bf16 cast (transient burst on idle CUs).
__global__ __launch_bounds__(512, 1) void lstm_persist(
    const u16* __restrict__ whh, const float* __restrict__ xg,
    u16* __restrict__ h2, unsigned* __restrict__ flags,
    const float* __restrict__ wout, u16* __restrict__ wout_bf) {
  __shared__ u16 hbuf[32 * 512];
  __shared__ u16 hloc[1024];
  const int tid = threadIdx.x;

  if (blockIdx.x >= LSTM_NBLK) {
    int idx = (blockIdx.x - LSTM_NBLK) * 512 + tid;
    int stride = (LSTM_GRID - LSTM_NBLK) * 512;
    for (int u2 = idx; u2 < 4096000; u2 += stride) {
      int e = u2 * 4; f32x4 v = *(const f32x4*)(wout + e);
      u16x4 o; o[0]=f2bf(v[0]); o[1]=f2bf(v[1]); o[2]=f2bf(v[2]); o[3]=f2bf(v[3]);
      *(u16x4*)(wout_bf + e) = o;
    }
    return;
  }

  const int w = tid >> 6, l = tid & 63;
  const int blk = blockIdx.x;
  const int j0 = (blk * 8 + w) * 4;                // wave's 4 h-columns
  const int c = l & 15;
  const int wrow = (c >> 2) * 512 + j0 + (c & 3);  // W_hh row == gate column
  const int ko = (l >> 4) * 8;
  u32* h2u = (u32*)h2;

  short8 bfr[16];
  const u16* wp = whh + wrow * 512 + ko;
#pragma unroll
  for (int kt = 0; kt < 16; ++kt) bfr[kt] = *(const short8*)(wp + kt * 32);

  const int rq = (l >> 4) * 4;
  const int jj = l & 3;
  const int b0 = l & 15, b1 = 16 + (l & 15);
  const int s0 = b0 & 7;

  // consumer stage mapping: thread covers (row cb, 32 k at ckg*32);
  // ckg == producer index; wave w covers ckg = 2w, 2w+1 exactly.
  const int cb = tid & 31;
  const int ckg = tid >> 5;        // 0..15
  const int csw = cb & 7;

  const int ob = tid >> 4;         // 0..31
  const int oj = tid & 15;         // 0..15

  float creg[2][4];
#pragma unroll
  for (int mt = 0; mt < 2; ++mt)
#pragma unroll
    for (int q = 0; q < 4; ++q) creg[mt][q] = 0.f;

  float xcur[2][4], xnext[2][4];
#pragma unroll
  for (int mt = 0; mt < 2; ++mt)
#pragma unroll
    for (int q = 0; q < 4; ++q)
      xcur[mt][q] = xg[(mt * 16 + rq + q) * 2048 + wrow];

  for (int it = 0; it < 64; ++it) {
    // ---- (A+B) per-wave: poll own 2 producers' flags, stage their slices ----
    if (it > 0) {
      const unsigned want = (unsigned)it;
      const unsigned* fl = flags + blk * 256 + ckg * 16;  // one line/half-wave
      for (;;) {
        unsigned f = ld_u32_sc_wait(fl);
        if (__all((int)(f >= want))) break;   // both of this wave's producers
      }
    }
    {
      const u16* src = h2 + it * 16384 + cb * 512 + ckg * 32;
      short8 d0 = ld_b128_sc(src);
      short8 d1 = ld_b128_sc(src + 8);
      short8 d2 = ld_b128_sc(src + 16);
      short8 d3 = ld_b128_sc(src + 24);
      waitcnt0();
      *(short8*)&hbuf[cb * 512 + (((ckg * 4 + 0) ^ csw) * 8)] = d0;
      *(short8*)&hbuf[cb * 512 + (((ckg * 4 + 1) ^ csw) * 8)] = d1;
      *(short8*)&hbuf[cb * 512 + (((ckg * 4 + 2) ^ csw) * 8)] = d2;
      *(short8*)&hbuf[cb * 512 + (((ckg * 4 + 3) ^ csw) * 8)] = d3;
    }
    __syncthreads();   // hbuf ready (single sync for poll+stage)

    // ---- (C) MFMA: gates = h_{prev} @ W_hh^T ----
    f32x4 acc0 = (f32x4){0.f, 0.f, 0.f, 0.f};
    f32x4 acc1 = (f32x4){0.f, 0.f, 0.f, 0.f};
#pragma unroll
    for (int kt = 0; kt < 16; ++kt) {
      int x = ((kt * 4 + (l >> 4)) ^ s0) * 8;
      short8 a0 = *(const short8*)&hbuf[b0 * 512 + x];
      short8 a1 = *(const short8*)&hbuf[b1 * 512 + x];
      acc0 = __builtin_amdgcn_mfma_f32_16x16x32_bf16(a0, bfr[kt], acc0, 0, 0, 0);
      acc1 = __builtin_amdgcn_mfma_f32_16x16x32_bf16(a1, bfr[kt], acc1, 0, 0, 0);
    }
    if (it < 63) {
#pragma unroll
      for (int mt = 0; mt < 2; ++mt)
#pragma unroll
        for (int q = 0; q < 4; ++q)
          xnext[mt][q] = xg[((it + 1) * 32 + mt * 16 + rq + q) * 2048 + wrow];
    }

    // ---- (D) pointwise LSTM cell -> hloc ----
#pragma unroll
    for (int mt = 0; mt < 2; ++mt) {
#pragma unroll
      for (int q = 0; q < 4; ++q) {
        float av = (mt == 0) ? acc0[q] : acc1[q];
        float gp = av + xcur[mt][q];
        int bl = (l & 48) | jj;
        float xi = __shfl(gp, bl);
        float xf = __shfl(gp, bl | 4);
        float xgg = __shfl(gp, bl | 8);
        float xo = __shfl(gp, bl | 12);
        float is = 1.f / (1.f + __expf(-xi));
        float fs = 1.f / (1.f + __expf(-xf));
        float e2 = __expf(2.f * xgg);
        float gt = 1.f - 2.f / (e2 + 1.f);       // tanh, inf-safe
        float os = 1.f / (1.f + __expf(-xo));
        float cn = fs * creg[mt][q] + is * gt;
        creg[mt][q] = cn;
        float e2c = __expf(2.f * cn);
        float hn = os * (1.f - 2.f / (e2c + 1.f));
        if ((l & 12) == 0) {
          int b = mt * 16 + rq + q;
          hloc[b * 32 + w * 4 + jj] = f2bf(hn);
        }
      }
    }
    __syncthreads();   // hloc complete (also separates C-reads from next stage)

    // ---- (E) publish block slice -> slot[it+1], full-line dwords ----
    {
      u32 v = *(const u32*)&hloc[ob * 32 + oj * 2];
      st_u32_sc(h2u + (it + 1) * 8192 + ob * 256 + blk * 16 + oj, v);
      waitcnt0();
    }
    __syncthreads();

    // ---- (F) flag (own line per consumer) + xg rotate ----
    if (it < 63) {
      if (w == 0 && l < 16)
        st_u32_sc(flags + l * 256 + blk * 16, (unsigned)(it + 1));
#pragma unroll
      for (int mt = 0; mt < 2; ++mt)
#pragma unroll
        for (int q = 0; q < 4; ++q)
          xcur[mt][q] = xnext[mt][q];
    }
  }
}

extern "C" void kernel_launch(void* const* d_in, const int* in_sizes, int n_in,
                              void* d_out, int out_size, void* d_ws, size_t ws_size,
                              hipStream_t stream) {
  (void)in_sizes; (void)n_in; (void)out_size; (void)ws_size;
  const float* iseq = (const float*)d_in[0];
  const float* h0   = (const float*)d_in[1];
  const float* wih  = (const float*)d_in[2];
  const float* whh  = (const float*)d_in[3];
  const float* bih  = (const float*)d_in[4];
  const float* bhh  = (const float*)d_in[5];
  const float* wout = (const float*)d_in[6];
  const float* bout = (const float*)d_in[7];

  char* ws = (char*)d_ws;
  u16* wout_bf = (u16*)(ws + 0);             // 32,768,000
  u16* wih_bf  = (u16*)(ws + 32768000);      // 2,097,152
  u16* whh_bf  = (u16*)(ws + 34865152);      // 2,097,152
  u16* ax      = (u16*)(ws + 36962304);      // 2,097,152
  u16* h2      = (u16*)(ws + 39059456);      // 65 slots x 32,768 = 2,129,920
  unsigned* flags = (unsigned*)(ws + 41189376); // 16,384 (16x16, 64B-padded)
  float* xg    = (float*)(ws + 41254912);    // 16,777,216  (end 58,032,128)
  float* out   = (float*)d_out;

  prep_kernel<<<2048, 256, 0, stream>>>(iseq, h0, wih, whh,
                                        wih_bf, whh_bf, ax, (u32*)h2, flags);
  // x_gates = A_x @ W_ih^T + b_ih + b_hh   -> xg [2048][2048] f32
  gemm_bt<<<256, 256, 0, stream>>>(ax, wih_bf, xg, bih, bhh, 2048);
  // persistent recurrence (16 sync blocks, per-wave poll+fetch) + Wout cast
  lstm_persist<<<LSTM_GRID, 512, 0, stream>>>(whh_bf, xg, h2, flags,
                                              wout, wout_bf);
  // logits = h @ W_out^T + b_out -> d_out [2048][32000] f32
  gemm2_256<<<2000, 512, 0, stream>>>(h2, wout_bf, out, bout, 32000);
}